// Round 16
// baseline (8627.087 us; speedup 1.0000x reference)
//
#include <hip/hip_runtime.h>

typedef __attribute__((ext_vector_type(8))) short short8;
typedef __attribute__((ext_vector_type(4))) float f32x4;
typedef __attribute__((ext_vector_type(4))) int int4v;
typedef __attribute__((ext_vector_type(4))) unsigned short u16x4;
typedef unsigned short u16;

#define T_LEN 256
#define BATCH 64
#define HID   1024
#define GDIM  4128
#define BH    65536
#define NWG   256

__device__ __forceinline__ u16 f2bf(float f){
  unsigned u = __builtin_bit_cast(unsigned, f);
  return (u16)((u + 0x7fffu + ((u >> 16) & 1u)) >> 16);
}

// ---- prologue kernels -------------------------------------------------------

__global__ __launch_bounds__(1024) void repackW(const float* __restrict__ Wih,
                                                const float* __restrict__ Whh,
                                                u16* __restrict__ Wt)
{
  __shared__ float tile[32][33];
  int k = blockIdx.x * 32 + threadIdx.y;
  int c = blockIdx.y * 32 + threadIdx.x;
  float v = (k < 1024) ? Wih[(size_t)k * GDIM + c]
                       : Whh[(size_t)(k - 1024) * GDIM + c];
  tile[threadIdx.y][threadIdx.x] = v;
  __syncthreads();
  int c2 = blockIdx.y * 32 + threadIdx.y;
  int k2 = blockIdx.x * 32 + threadIdx.x;
  Wt[(size_t)c2 * 2048 + k2] = f2bf(tile[threadIdx.x][threadIdx.y]);
}

__global__ __launch_bounds__(256) void gatherX(const int* __restrict__ tokens,
                                               const float* __restrict__ emb,
                                               u16* __restrict__ x,
                                               float* __restrict__ maskout)
{
  int idx = blockIdx.x;
  int tok = tokens[idx];
  const f32x4* src = (const f32x4*)&emb[(size_t)tok * HID];
  f32x4 v = src[threadIdx.x];
  u16x4 o;
  #pragma unroll
  for (int j = 0; j < 4; ++j) o[j] = f2bf(v[j]);
  *(u16x4*)&x[(size_t)idx * HID + threadIdx.x * 4] = o;
  if (threadIdx.x == 0) maskout[idx] = (tok != 0) ? 1.0f : 0.0f;
}

__global__ __launch_bounds__(256) void biasK(const float* __restrict__ bih0, const float* __restrict__ bhh0,
                                             const float* __restrict__ bih1, const float* __restrict__ bhh1,
                                             float* __restrict__ bias0, float* __restrict__ bias1)
{
  int i = blockIdx.x * 256 + threadIdx.x;
  if (i < GDIM){ bias0[i] = bih0[i] + bhh0[i]; bias1[i] = bih1[i] + bhh1[i]; }
}

// ---- fused persistent kernel ------------------------------------------------
// Round-13 base (best: 7.80ms) + HEATER WAVES (clock-governor experiment).
// 768 thr = 12 waves: waves 0-7 = workers (identical to r13), waves 8-11 =
// heaters issuing dummy MFMAs continuously through every worker phase,
// released per-phase by an LDS segment counter written by worker tid0.
// Heaters join every __syncthreads (matched count via the same act/s logic).
__global__ __launch_bounds__(768, 1) void persist(
    const u16* __restrict__ Wt0, const u16* __restrict__ Wt1,
    const float* __restrict__ bias0, const float* __restrict__ bias1,
    const u16* __restrict__ x, u16* __restrict__ hA, u16* __restrict__ hB,
    float* __restrict__ out, unsigned* __restrict__ slots)
{
  __shared__ __align__(16) u16 Ws[32 * 2048];      // 128KB rest weights (ih+hh)
  __shared__ __align__(16) float smT[32 * 68];     // sm logits, [col][row]
  __shared__ __align__(16) float restT[32 * 68];   // rest gates, [col][row]
  __shared__ __align__(16) u16 hStage[64 * 8];     // bf16 h, [row][elem]
  __shared__ __align__(16) float oStage[64 * 8];   // f32 h2, [row][elem]
  __shared__ unsigned lseg;                        // phase counter for heaters

  const int wg = blockIdx.x, tid = threadIdx.x;
  const int lane = tid & 63, wave = tid >> 6;
  const int lo = lane & 15, hi = lane >> 4, khi = hi * 8;
  const int mt = wave >> 1, nw = wave & 1;         // workers: 4 M-tiles x 2
  const int row = mt * 16 + lo;
  const int lay = wg >> 7;
  const int E0 = (wg & 127) * 8;
  const u16* Wt = lay ? Wt1 : Wt0;
  const float* bias = lay ? bias1 : bias0;
  const bool worker = (tid < 512);

  auto gcol = [&](int c){ return 32 + (c >> 3) * 1024 + E0 + (c & 7); };

  if (tid == 0) lseg = 0;
  // one-time staging: 32 rest cols x K=2048, XOR-swizzled (16B-preserving)
  for (int i = tid; i < 32 * 256; i += 768){
    int c = i >> 8, ck = (i & 255) << 3;
    *(int4v*)&Ws[c * 2048 + (ck ^ ((c & 7) << 3))] =
        *(const int4v*)&Wt[(size_t)gcol(c) * 2048 + ck];
  }

  // per-wave tiles (workers): nw=0 -> sm cols (global B); nw=1 -> rest local
  float bv0 = 0.f, bv1 = 0.f;
  const u16 *gB0 = nullptr, *gB1 = nullptr;
  if (worker){
    if (nw == 0){
      bv0 = bias[lo]; bv1 = bias[16 + lo];
      gB0 = Wt + (size_t)lo * 2048;
      gB1 = Wt + (size_t)(16 + lo) * 2048;
    } else {
      bv0 = bias[gcol(lo)]; bv1 = bias[gcol(16 + lo)];
    }
  }
  __syncthreads();

  auto ldsB = [&](int c, int k)->short8 {
    return *(const short8*)&Ws[c * 2048 + (k ^ ((c & 7) << 3))];
  };

  f32x4 xn0, xn1;                    // slack accumulators (bias + ih-part)
  auto slack_mm = [&](const u16* Asrc){
    f32x4 s0 = {bv0,bv0,bv0,bv0}, s1 = {bv1,bv1,bv1,bv1};
    const u16* pA = Asrc + (size_t)row * HID;
    if (nw == 0){
      #pragma unroll 1
      for (int blk = 0; blk < 4; ++blk){
        short8 A[8], B0[8], B1[8];
        #pragma unroll
        for (int i = 0; i < 8; ++i){
          int k = (blk * 8 + i) * 32 + khi;
          A[i]  = *(const short8*)(pA + k);
          B0[i] = *(const short8*)(gB0 + k);
          B1[i] = *(const short8*)(gB1 + k);
        }
        #pragma unroll
        for (int i = 0; i < 8; ++i){
          s0 = __builtin_amdgcn_mfma_f32_16x16x32_bf16(A[i], B0[i], s0, 0,0,0);
          s1 = __builtin_amdgcn_mfma_f32_16x16x32_bf16(A[i], B1[i], s1, 0,0,0);
        }
      }
    } else {
      #pragma unroll 1
      for (int blk = 0; blk < 4; ++blk){
        short8 A[8];
        #pragma unroll
        for (int i = 0; i < 8; ++i)
          A[i] = *(const short8*)(pA + (blk * 8 + i) * 32 + khi);
        #pragma unroll
        for (int i = 0; i < 8; ++i){
          int k = (blk * 8 + i) * 32 + khi;
          s0 = __builtin_amdgcn_mfma_f32_16x16x32_bf16(A[i], ldsB(lo, k), s0, 0,0,0);
          s1 = __builtin_amdgcn_mfma_f32_16x16x32_bf16(A[i], ldsB(16 + lo, k), s1, 0,0,0);
        }
      }
    }
    xn0 = s0; xn1 = s1;
  };

  // heater state: dummy MFMA streams (a=1.0bf16, b=0 -> acc stays 0)
  short8 hone; {
    #pragma unroll
    for (int i = 0; i < 8; ++i) hone[i] = (short)0x3F80;
  }
  short8 hzero = {0,0,0,0,0,0,0,0};
  f32x4 h0 = {0,0,0,0}, h1 = {0,0,0,0}, h2 = {0,0,0,0}, h3 = {0,0,0,0};
  auto heatwait = [&](unsigned tg){
    while (*(volatile const unsigned*)&lseg < tg){
      #pragma unroll
      for (int i = 0; i < 16; ++i){
        h0 = __builtin_amdgcn_mfma_f32_16x16x32_bf16(hone, hzero, h0, 0,0,0);
        h1 = __builtin_amdgcn_mfma_f32_16x16x32_bf16(hone, hzero, h1, 0,0,0);
        h2 = __builtin_amdgcn_mfma_f32_16x16x32_bf16(hone, hzero, h2, 0,0,0);
        h3 = __builtin_amdgcn_mfma_f32_16x16x32_bf16(hone, hzero, h3, 0,0,0);
      }
    }
  };

  float creg = 0.f;                  // c-state: one scalar per thread
  if (worker && lay == 0) slack_mm(x);  // xn for t=0

  unsigned segc = 0;
  for (int s = 0; s <= 257; ++s){
    const int t = lay ? (s - 2) : s;
    const bool act = (t >= 0) && (t < T_LEN);
    if (act){
      if (worker){
        f32x4 a0 = xn0, a1 = xn1;
        if (t > 0){
          const u16* Asrc = lay ? (hB + (size_t)(t - 1) * BH)
                                : (hA + (size_t)(s - 1) * BH);
          const u16* pA = Asrc + (size_t)row * HID;
          if (nw == 0){
            #pragma unroll 1
            for (int blk = 0; blk < 4; ++blk){
              short8 A[8], B0[8], B1[8];
              #pragma unroll
              for (int i = 0; i < 8; ++i){
                int k = (blk * 8 + i) * 32 + khi;
                A[i]  = *(const short8*)(pA + k);
                B0[i] = *(const short8*)(gB0 + 1024 + k);
                B1[i] = *(const short8*)(gB1 + 1024 + k);
              }
              #pragma unroll
              for (int i = 0; i < 8; ++i){
                a0 = __builtin_amdgcn_mfma_f32_16x16x32_bf16(A[i], B0[i], a0, 0,0,0);
                a1 = __builtin_amdgcn_mfma_f32_16x16x32_bf16(A[i], B1[i], a1, 0,0,0);
              }
            }
          } else {
            #pragma unroll 1
            for (int blk = 0; blk < 4; ++blk){
              short8 A[8];
              #pragma unroll
              for (int i = 0; i < 8; ++i)
                A[i] = *(const short8*)(pA + (blk * 8 + i) * 32 + khi);
              #pragma unroll
              for (int i = 0; i < 8; ++i){
                int k = (blk * 8 + i) * 32 + khi;
                a0 = __builtin_amdgcn_mfma_f32_16x16x32_bf16(A[i], ldsB(lo, 1024 + k), a0, 0,0,0);
                a1 = __builtin_amdgcn_mfma_f32_16x16x32_bf16(A[i], ldsB(16 + lo, 1024 + k), a1, 0,0,0);
              }
            }
          }
        }
        // transpose acc -> per-row (C/D: col=lane&15, row=(lane>>4)*4+j)
        const int r0i = mt * 16 + hi * 4;
        if (nw == 0){
          *(f32x4*)&smT[lo * 68 + r0i] = a0;
          *(f32x4*)&smT[(16 + lo) * 68 + r0i] = a1;
        } else {
          *(f32x4*)&restT[lo * 68 + r0i] = a0;
          *(f32x4*)&restT[(16 + lo) * 68 + r0i] = a1;
        }
      }
      ++segc;
      if (tid == 0) *(volatile unsigned*)&lseg = segc;
      if (!worker) heatwait(segc);
      __syncthreads();
      if (worker){
        // gating: thread -> (row r, elem E0+j); results staged in LDS
        const int r = tid >> 3, j = tid & 7;
        const int n = (wg & 127) >> 3;
        float m1 = -1e30f, m2 = -1e30f;
        float l1[16], l2[16];
        #pragma unroll
        for (int i = 0; i < 16; ++i){
          l1[i] = smT[i * 68 + r]; l2[i] = smT[(16 + i) * 68 + r];
          m1 = fmaxf(m1, l1[i]);   m2 = fmaxf(m2, l2[i]);
        }
        float s1 = 0.f, s2 = 0.f, cu1 = 0.f, cu2 = 0.f;
        #pragma unroll
        for (int i = 0; i < 16; ++i){
          float e1 = __expf(l1[i] - m1), e2 = __expf(l2[i] - m2);
          s1 += e1; s2 += e2;
          if (i <= n){ cu1 += e1; cu2 += e2; }
        }
        const float cin = 1.f - cu1 / s1;
        const float cf  = cu2 / s2;
        const float ov  = cf * cin;
        const float og = restT[j * 68 + r];
        const float ce = restT[(8 + j) * 68 + r];
        const float ig = restT[(16 + j) * 68 + r];
        const float fg = restT[(24 + j) * 68 + r];
        const float ogv = 1.f / (1.f + __expf(-og));
        const float inv = 1.f / (1.f + __expf(-ig));
        const float fgv = 1.f / (1.f + __expf(-fg));
        const float cev = tanhf(ce);
        if (t == 0) creg = 0.f;
        const float fga = fgv * ov + (cf - ov);
        const float iga = inv * ov + (cin - ov);
        const float cy  = fga * creg + iga * cev;
        creg = cy;
        const float hy = ogv * tanhf(cy);
        hStage[r * 8 + j] = f2bf(hy);
        if (lay) oStage[r * 8 + j] = hy;
      }
      ++segc;
      if (tid == 0) *(volatile unsigned*)&lseg = segc;
      if (!worker) heatwait(segc);
      __syncthreads();
      // coalesced handoff: wave0 -> h (volatile 16B/lane) + WAVE-LOCAL drain
      // + slot store. Waves 1-2 -> out, no drain (no device consumer).
      if (tid < 64){
        int4v hv = *(const int4v*)&hStage[tid * 8];
        u16* dst = (lay ? hB : hA) + (size_t)t * BH + tid * HID + E0;
        *(volatile int4v*)dst = hv;
        asm volatile("s_waitcnt vmcnt(0)" ::: "memory");
        if (tid == 0) *(volatile unsigned*)&slots[wg] = (unsigned)(s + 1);
      } else if (lay && tid >= 64 && tid < 192){
        int w = tid - 64;
        int r = w >> 1, half = w & 1;
        f32x4 ov4 = *(const f32x4*)&oStage[r * 8 + half * 4];
        *(f32x4*)&out[((size_t)t * BATCH + r) * HID + E0 + half * 4] = ov4;
      }
    } else {
      if (tid == 0) *(volatile unsigned*)&slots[wg] = (unsigned)(s + 1);
    }
    // ---- slack: next epoch's ih-product (LDS/L2 weights) ----
    if (worker){
      if (lay == 0){
        if (s <= T_LEN - 2) slack_mm(x + (size_t)(s + 1) * BH);
      } else {
        if (s >= 1 && s <= T_LEN) slack_mm(hA + (size_t)(s - 1) * BH);
      }
    }
    // ---- barrier: wave-0 busy-scans all 256 packed slots; heaters burn ----
    if (s < 257){
      const unsigned tg = (unsigned)(s + 1);
      if (tid < 64){
        const volatile int4v* sp = (const volatile int4v*)&slots[tid * 4];
        for (;;){
          int4v v = *sp;
          int ok = ((unsigned)v[0] >= tg) & ((unsigned)v[1] >= tg) &
                   ((unsigned)v[2] >= tg) & ((unsigned)v[3] >= tg);
          if (__all(ok)) break;
        }
      }
      ++segc;
      if (tid == 0) *(volatile unsigned*)&lseg = segc;
      if (!worker) heatwait(segc);
      __syncthreads();
    }
  }
  asm volatile("" :: "v"(h0), "v"(h1), "v"(h2), "v"(h3));
}

// ---- launch -----------------------------------------------------------------

extern "C" void kernel_launch(void* const* d_in, const int* in_sizes, int n_in,
                              void* d_out, int out_size, void* d_ws, size_t ws_size,
                              hipStream_t stream)
{
  (void)in_sizes; (void)n_in; (void)out_size; (void)ws_size;
  const int*   tokens = (const int*)d_in[0];
  const float* emb    = (const float*)d_in[1];
  const float* Wih0   = (const float*)d_in[2];
  const float* bih0   = (const float*)d_in[3];
  const float* Whh0   = (const float*)d_in[4];
  const float* bhh0   = (const float*)d_in[5];
  const float* Wih1   = (const float*)d_in[6];
  const float* bih1   = (const float*)d_in[7];
  const float* Whh1   = (const float*)d_in[8];
  const float* bhh1   = (const float*)d_in[9];
  float* out = (float*)d_out;

  char* ws = (char*)d_ws;
  u16*   Wt0    = (u16*)(ws);                     // 16,908,288
  u16*   Wt1    = (u16*)(ws + 16908288);          // 16,908,288
  u16*   x      = (u16*)(ws + 33816576);          // 33,554,432
  u16*   hA     = (u16*)(ws + 67371008);          // 33,554,432 (h1 full history)
  u16*   hB     = (u16*)(ws + 100925440);         // 33,554,432 (h2 full history)
  float* bias0  = (float*)(ws + 134479872);       // 16,512
  float* bias1  = (float*)(ws + 134496384);       // 16,512
  unsigned* slots = (unsigned*)(ws + 134512896);  // 1,024 (256 x 4B packed)
  // total 134,513,920 bytes

  repackW<<<dim3(64,129), dim3(32,32), 0, stream>>>(Wih0, Whh0, Wt0);
  repackW<<<dim3(64,129), dim3(32,32), 0, stream>>>(Wih1, Whh1, Wt1);
  gatherX<<<16384, 256, 0, stream>>>(tokens, emb, x, out + 16777216);
  biasK<<<17, 256, 0, stream>>>(bih0, bhh0, bih1, bhh1, bias0, bias1);
  hipMemsetAsync(slots, 0, 1024, stream);

  persist<<<NWG, 768, 0, stream>>>(Wt0, Wt1, bias0, bias1, x, hA, hB,
                                   out, slots);
}

// Round 17
// 7815.323 us; speedup vs baseline: 1.1039x; 1.1039x over previous
//
#include <hip/hip_runtime.h>

typedef __attribute__((ext_vector_type(8))) short short8;
typedef __attribute__((ext_vector_type(4))) float f32x4;
typedef __attribute__((ext_vector_type(4))) int int4v;
typedef __attribute__((ext_vector_type(4))) unsigned short u16x4;
typedef unsigned short u16;

#define T_LEN 256
#define BATCH 64
#define HID   1024
#define GDIM  4128
#define BH    65536
#define NWG   256

__device__ __forceinline__ u16 f2bf(float f){
  unsigned u = __builtin_bit_cast(unsigned, f);
  return (u16)((u + 0x7fffu + ((u >> 16) & 1u)) >> 16);
}

// ---- prologue kernels -------------------------------------------------------

__global__ __launch_bounds__(1024) void repackW(const float* __restrict__ Wih,
                                                const float* __restrict__ Whh,
                                                u16* __restrict__ Wt)
{
  __shared__ float tile[32][33];
  int k = blockIdx.x * 32 + threadIdx.y;
  int c = blockIdx.y * 32 + threadIdx.x;
  float v = (k < 1024) ? Wih[(size_t)k * GDIM + c]
                       : Whh[(size_t)(k - 1024) * GDIM + c];
  tile[threadIdx.y][threadIdx.x] = v;
  __syncthreads();
  int c2 = blockIdx.y * 32 + threadIdx.y;
  int k2 = blockIdx.x * 32 + threadIdx.x;
  Wt[(size_t)c2 * 2048 + k2] = f2bf(tile[threadIdx.x][threadIdx.y]);
}

__global__ __launch_bounds__(256) void gatherX(const int* __restrict__ tokens,
                                               const float* __restrict__ emb,
                                               u16* __restrict__ x,
                                               float* __restrict__ maskout)
{
  int idx = blockIdx.x;
  int tok = tokens[idx];
  const f32x4* src = (const f32x4*)&emb[(size_t)tok * HID];
  f32x4 v = src[threadIdx.x];
  u16x4 o;
  #pragma unroll
  for (int j = 0; j < 4; ++j) o[j] = f2bf(v[j]);
  *(u16x4*)&x[(size_t)idx * HID + threadIdx.x * 4] = o;
  if (threadIdx.x == 0) maskout[idx] = (tok != 0) ? 1.0f : 0.0f;
}

__global__ __launch_bounds__(256) void biasK(const float* __restrict__ bih0, const float* __restrict__ bhh0,
                                             const float* __restrict__ bih1, const float* __restrict__ bhh1,
                                             float* __restrict__ bias0, float* __restrict__ bias1)
{
  int i = blockIdx.x * 256 + threadIdx.x;
  if (i < GDIM){ bias0[i] = bih0[i] + bhh0[i]; bias1[i] = bih1[i] + bhh1[i]; }
}

// ---- fused persistent kernel ------------------------------------------------
// Round-13 base (best: 7.80ms) with DECOUPLED PER-LAYER BARRIERS:
// L0 (wg 0..127) scans only L0 slots and free-runs its 256-step recurrence
// (its dataflow depends on no L1 data); L1 scans all 256, but L0 runs ahead
// so L1's effective tail set is its own 128. L0 parks its slot at 1000 when
// done. Everything else byte-identical to r13.
__global__ __launch_bounds__(512, 1) void persist(
    const u16* __restrict__ Wt0, const u16* __restrict__ Wt1,
    const float* __restrict__ bias0, const float* __restrict__ bias1,
    const u16* __restrict__ x, u16* __restrict__ hA, u16* __restrict__ hB,
    float* __restrict__ out, unsigned* __restrict__ slots)
{
  __shared__ __align__(16) u16 Ws[32 * 2048];      // 128KB rest weights (ih+hh)
  __shared__ __align__(16) float smT[32 * 68];     // sm logits, [col][row]
  __shared__ __align__(16) float restT[32 * 68];   // rest gates, [col][row]
  __shared__ __align__(16) u16 hStage[64 * 8];     // bf16 h, [row][elem]
  __shared__ __align__(16) float oStage[64 * 8];   // f32 h2, [row][elem]

  const int wg = blockIdx.x, tid = threadIdx.x;
  const int lane = tid & 63, wave = tid >> 6;
  const int lo = lane & 15, hi = lane >> 4, khi = hi * 8;
  const int mt = wave >> 1, nw = wave & 1;         // 4 M-tiles x 2 tile-groups
  const int row = mt * 16 + lo;
  const int lay = wg >> 7;
  const int E0 = (wg & 127) * 8;
  const u16* Wt = lay ? Wt1 : Wt0;
  const float* bias = lay ? bias1 : bias0;

  auto gcol = [&](int c){ return 32 + (c >> 3) * 1024 + E0 + (c & 7); };

  // one-time staging: 32 rest cols x K=2048, XOR-swizzled (16B-preserving)
  for (int i = tid; i < 32 * 256; i += 512){
    int c = i >> 8, ck = (i & 255) << 3;
    *(int4v*)&Ws[c * 2048 + (ck ^ ((c & 7) << 3))] =
        *(const int4v*)&Wt[(size_t)gcol(c) * 2048 + ck];
  }

  // per-wave tiles: nw=0 -> sm cols {lo,16+lo} (global B); nw=1 -> rest local
  float bv0, bv1;
  const u16 *gB0 = nullptr, *gB1 = nullptr;
  if (nw == 0){
    bv0 = bias[lo]; bv1 = bias[16 + lo];
    gB0 = Wt + (size_t)lo * 2048;
    gB1 = Wt + (size_t)(16 + lo) * 2048;
  } else {
    bv0 = bias[gcol(lo)]; bv1 = bias[gcol(16 + lo)];
  }
  __syncthreads();

  auto ldsB = [&](int c, int k)->short8 {
    return *(const short8*)&Ws[c * 2048 + (k ^ ((c & 7) << 3))];
  };

  f32x4 xn0, xn1;                    // slack accumulators (bias + ih-part)
  auto slack_mm = [&](const u16* Asrc){
    f32x4 s0 = {bv0,bv0,bv0,bv0}, s1 = {bv1,bv1,bv1,bv1};
    const u16* pA = Asrc + (size_t)row * HID;
    if (nw == 0){
      #pragma unroll 1
      for (int blk = 0; blk < 4; ++blk){
        short8 A[8], B0[8], B1[8];
        #pragma unroll
        for (int i = 0; i < 8; ++i){
          int k = (blk * 8 + i) * 32 + khi;
          A[i]  = *(const short8*)(pA + k);
          B0[i] = *(const short8*)(gB0 + k);
          B1[i] = *(const short8*)(gB1 + k);
        }
        #pragma unroll
        for (int i = 0; i < 8; ++i){
          s0 = __builtin_amdgcn_mfma_f32_16x16x32_bf16(A[i], B0[i], s0, 0,0,0);
          s1 = __builtin_amdgcn_mfma_f32_16x16x32_bf16(A[i], B1[i], s1, 0,0,0);
        }
      }
    } else {
      #pragma unroll 1
      for (int blk = 0; blk < 4; ++blk){
        short8 A[8];
        #pragma unroll
        for (int i = 0; i < 8; ++i)
          A[i] = *(const short8*)(pA + (blk * 8 + i) * 32 + khi);
        #pragma unroll
        for (int i = 0; i < 8; ++i){
          int k = (blk * 8 + i) * 32 + khi;
          s0 = __builtin_amdgcn_mfma_f32_16x16x32_bf16(A[i], ldsB(lo, k), s0, 0,0,0);
          s1 = __builtin_amdgcn_mfma_f32_16x16x32_bf16(A[i], ldsB(16 + lo, k), s1, 0,0,0);
        }
      }
    }
    xn0 = s0; xn1 = s1;
  };

  float creg = 0.f;                  // c-state: one scalar per thread
  if (lay == 0) slack_mm(x);         // xn for t=0

  for (int s = 0; s <= 257; ++s){
    if (lay == 0 && s > T_LEN - 1) break;     // L0 done (slot parked at 1000)
    const int t = lay ? (s - 2) : s;
    const bool act = (t >= 0) && (t < T_LEN);
    const unsigned slotv = (lay == 0 && s == T_LEN - 1) ? 1000u : (unsigned)(s + 1);
    if (act){
      f32x4 a0 = xn0, a1 = xn1;
      if (t > 0){
        const u16* Asrc = lay ? (hB + (size_t)(t - 1) * BH)
                              : (hA + (size_t)(s - 1) * BH);
        const u16* pA = Asrc + (size_t)row * HID;
        if (nw == 0){
          #pragma unroll 1
          for (int blk = 0; blk < 4; ++blk){
            short8 A[8], B0[8], B1[8];
            #pragma unroll
            for (int i = 0; i < 8; ++i){
              int k = (blk * 8 + i) * 32 + khi;
              A[i]  = *(const short8*)(pA + k);
              B0[i] = *(const short8*)(gB0 + 1024 + k);
              B1[i] = *(const short8*)(gB1 + 1024 + k);
            }
            #pragma unroll
            for (int i = 0; i < 8; ++i){
              a0 = __builtin_amdgcn_mfma_f32_16x16x32_bf16(A[i], B0[i], a0, 0,0,0);
              a1 = __builtin_amdgcn_mfma_f32_16x16x32_bf16(A[i], B1[i], a1, 0,0,0);
            }
          }
        } else {
          #pragma unroll 1
          for (int blk = 0; blk < 4; ++blk){
            short8 A[8];
            #pragma unroll
            for (int i = 0; i < 8; ++i)
              A[i] = *(const short8*)(pA + (blk * 8 + i) * 32 + khi);
            #pragma unroll
            for (int i = 0; i < 8; ++i){
              int k = (blk * 8 + i) * 32 + khi;
              a0 = __builtin_amdgcn_mfma_f32_16x16x32_bf16(A[i], ldsB(lo, 1024 + k), a0, 0,0,0);
              a1 = __builtin_amdgcn_mfma_f32_16x16x32_bf16(A[i], ldsB(16 + lo, 1024 + k), a1, 0,0,0);
            }
          }
        }
      }
      // transpose acc -> per-row layout (C/D: col=lane&15, row=(lane>>4)*4+j)
      const int r0i = mt * 16 + hi * 4;
      if (nw == 0){
        *(f32x4*)&smT[lo * 68 + r0i] = a0;
        *(f32x4*)&smT[(16 + lo) * 68 + r0i] = a1;
      } else {
        *(f32x4*)&restT[lo * 68 + r0i] = a0;
        *(f32x4*)&restT[(16 + lo) * 68 + r0i] = a1;
      }
      __syncthreads();
      // gating: thread -> (row r, elem E0+j); results staged in LDS
      {
        const int r = tid >> 3, j = tid & 7;
        const int n = (wg & 127) >> 3;
        float m1 = -1e30f, m2 = -1e30f;
        float l1[16], l2[16];
        #pragma unroll
        for (int i = 0; i < 16; ++i){
          l1[i] = smT[i * 68 + r]; l2[i] = smT[(16 + i) * 68 + r];
          m1 = fmaxf(m1, l1[i]);   m2 = fmaxf(m2, l2[i]);
        }
        float s1 = 0.f, s2 = 0.f, cu1 = 0.f, cu2 = 0.f;
        #pragma unroll
        for (int i = 0; i < 16; ++i){
          float e1 = __expf(l1[i] - m1), e2 = __expf(l2[i] - m2);
          s1 += e1; s2 += e2;
          if (i <= n){ cu1 += e1; cu2 += e2; }
        }
        const float cin = 1.f - cu1 / s1;
        const float cf  = cu2 / s2;
        const float ov  = cf * cin;
        const float og = restT[j * 68 + r];
        const float ce = restT[(8 + j) * 68 + r];
        const float ig = restT[(16 + j) * 68 + r];
        const float fg = restT[(24 + j) * 68 + r];
        const float ogv = 1.f / (1.f + __expf(-og));
        const float inv = 1.f / (1.f + __expf(-ig));
        const float fgv = 1.f / (1.f + __expf(-fg));
        const float cev = tanhf(ce);
        if (t == 0) creg = 0.f;
        const float fga = fgv * ov + (cf - ov);
        const float iga = inv * ov + (cin - ov);
        const float cy  = fga * creg + iga * cev;
        creg = cy;
        const float hy = ogv * tanhf(cy);
        hStage[r * 8 + j] = f2bf(hy);
        if (lay) oStage[r * 8 + j] = hy;
      }
      __syncthreads();
      // coalesced handoff: wave0 -> h (volatile 16B/lane) + WAVE-LOCAL drain
      // + slot store. Waves 1-2 -> out, no drain (no device consumer).
      if (tid < 64){
        int4v hv = *(const int4v*)&hStage[tid * 8];
        u16* dst = (lay ? hB : hA) + (size_t)t * BH + tid * HID + E0;
        *(volatile int4v*)dst = hv;
        asm volatile("s_waitcnt vmcnt(0)" ::: "memory");
        if (tid == 0) *(volatile unsigned*)&slots[wg] = slotv;
      } else if (lay && tid < 192){
        int w = tid - 64;
        int r = w >> 1, half = w & 1;
        f32x4 ov4 = *(const f32x4*)&oStage[r * 8 + half * 4];
        *(f32x4*)&out[((size_t)t * BATCH + r) * HID + E0 + half * 4] = ov4;
      }
    } else {
      if (tid == 0) *(volatile unsigned*)&slots[wg] = slotv;
    }
    // ---- slack: next epoch's ih-product (LDS/L2 weights) ----
    if (lay == 0){
      if (s <= T_LEN - 2) slack_mm(x + (size_t)(s + 1) * BH);
    } else {
      if (s >= 1 && s <= T_LEN) slack_mm(hA + (size_t)(s - 1) * BH);
    }
    // ---- barrier: per-layer decoupled busy-scan ----
    if (lay == 0){
      if (s < T_LEN - 1){
        const unsigned tg = (unsigned)(s + 1);
        if (tid < 64){
          // lanes 0..31 cover L0 slots[0..127]; lanes 32..63 idle (ok=1)
          const volatile int4v* sp =
              (const volatile int4v*)&slots[(lane & 31) * 4];
          for (;;){
            int4v v = *sp;
            int ok = (lane < 32)
                   ? (((unsigned)v[0] >= tg) & ((unsigned)v[1] >= tg) &
                      ((unsigned)v[2] >= tg) & ((unsigned)v[3] >= tg))
                   : 1;
            if (__all(ok)) break;
          }
        }
        __syncthreads();
      }
    } else {
      if (s < 257){
        const unsigned tg = (unsigned)(s + 1);
        if (tid < 64){
          const volatile int4v* sp = (const volatile int4v*)&slots[tid * 4];
          for (;;){
            int4v v = *sp;
            int ok = ((unsigned)v[0] >= tg) & ((unsigned)v[1] >= tg) &
                     ((unsigned)v[2] >= tg) & ((unsigned)v[3] >= tg);
            if (__all(ok)) break;
          }
        }
        __syncthreads();
      }
    }
  }
}

// ---- launch -----------------------------------------------------------------

extern "C" void kernel_launch(void* const* d_in, const int* in_sizes, int n_in,
                              void* d_out, int out_size, void* d_ws, size_t ws_size,
                              hipStream_t stream)
{
  (void)in_sizes; (void)n_in; (void)out_size; (void)ws_size;
  const int*   tokens = (const int*)d_in[0];
  const float* emb    = (const float*)d_in[1];
  const float* Wih0   = (const float*)d_in[2];
  const float* bih0   = (const float*)d_in[3];
  const float* Whh0   = (const float*)d_in[4];
  const float* bhh0   = (const float*)d_in[5];
  const float* Wih1   = (const float*)d_in[6];
  const float* bih1   = (const float*)d_in[7];
  const float* Whh1   = (const float*)d_in[8];
  const float* bhh1   = (const float*)d_in[9];
  float* out = (float*)d_out;

  char* ws = (char*)d_ws;
  u16*   Wt0    = (u16*)(ws);                     // 16,908,288
  u16*   Wt1    = (u16*)(ws + 16908288);          // 16,908,288
  u16*   x      = (u16*)(ws + 33816576);          // 33,554,432
  u16*   hA     = (u16*)(ws + 67371008);          // 33,554,432 (h1 full history)
  u16*   hB     = (u16*)(ws + 100925440);         // 33,554,432 (h2 full history)
  float* bias0  = (float*)(ws + 134479872);       // 16,512
  float* bias1  = (float*)(ws + 134496384);       // 16,512
  unsigned* slots = (unsigned*)(ws + 134512896);  // 1,024 (256 x 4B packed)
  // total 134,513,920 bytes

  repackW<<<dim3(64,129), dim3(32,32), 0, stream>>>(Wih0, Whh0, Wt0);
  repackW<<<dim3(64,129), dim3(32,32), 0, stream>>>(Wih1, Whh1, Wt1);
  gatherX<<<16384, 256, 0, stream>>>(tokens, emb, x, out + 16777216);
  biasK<<<17, 256, 0, stream>>>(bih0, bhh0, bih1, bhh1, bias0, bias1);
  hipMemsetAsync(slots, 0, 1024, stream);

  persist<<<NWG, 512, 0, stream>>>(Wt0, Wt1, bias0, bias1, x, hA, hB,
                                   out, slots);
}